// Round 11
// baseline (2222.297 us; speedup 1.0000x reference)
//
#include <hip/hip_runtime.h>

// ---------------------------------------------------------------------------
// Qwen3-style 8-layer transformer forward on MI355X (gfx950).
// Round 11: gemm256_k was LDS-read-bound (96 ds_read_b128/K-tile = 1152 cyc
// vs 516 cyc MFMA).  A-operand now loads direct global->VGPR (L1/L2-served,
// A is L3-resident); LDS keeps only the 4-slot B ring.  LDS reads/K-tile
// drop 3x -> MFMA-bound.  Small gemm_k / fattn / rest = round-8 exactly.
// ---------------------------------------------------------------------------

typedef unsigned short u16;
typedef __bf16  bf16x8 __attribute__((ext_vector_type(8)));   // 4 VGPRs
typedef unsigned short u16x8 __attribute__((ext_vector_type(8)));
typedef float   f32x4  __attribute__((ext_vector_type(4)));

#define DEV static __device__ __forceinline__

constexpr int NB  = 2;
constexpr int S   = 1024;
constexpr int NT  = NB * S;
constexpr int H   = 1024;
constexpr int NH  = 16;
constexpr int NKV = 8;
constexpr int HD  = 64;
constexpr int NL  = 8;
constexpr int FF  = 4096;
constexpr int V   = 32000;
constexpr int QKVW = 2048;

DEV float b2f(u16 x) { return __uint_as_float(((unsigned)x) << 16); }
DEV u16   f2b(float f) {
  unsigned i = __float_as_uint(f);
  return (u16)((i + 0x7fffu + ((i >> 16) & 1u)) >> 16);   // RNE
}

DEV void gload16(const void* g, void* l) {
  __builtin_amdgcn_global_load_lds(
      (const __attribute__((address_space(1))) void*)g,
      (__attribute__((address_space(3))) void*)l, 16, 0, 0);
}

DEV bf16x8 ld128(const u16* p) { return *reinterpret_cast<const bf16x8*>(p); }

template <int N> DEV void waitvm() {
  if constexpr (N == 0)       asm volatile("s_waitcnt vmcnt(0)" ::: "memory");
  else if constexpr (N == 2)  asm volatile("s_waitcnt vmcnt(2)" ::: "memory");
  else if constexpr (N == 3)  asm volatile("s_waitcnt vmcnt(3)" ::: "memory");
  else if constexpr (N == 4)  asm volatile("s_waitcnt vmcnt(4)" ::: "memory");
  else if constexpr (N == 6)  asm volatile("s_waitcnt vmcnt(6)" ::: "memory");
  else if constexpr (N == 8)  asm volatile("s_waitcnt vmcnt(8)" ::: "memory");
  else if constexpr (N == 10) asm volatile("s_waitcnt vmcnt(10)" ::: "memory");
  else                        asm volatile("s_waitcnt vmcnt(12)" ::: "memory");
}

// ---------------------------------------------------------------------------
// 256x256-tile GEMM, BK=32.  B through a 4-slot LDS ring (depth-2 prefetch,
// counted vmcnt, never 0 in steady state).  A direct global->VGPR with
// 1-tile register double-buffer (aE/aO, static indexing).  512 thr = 8 waves
// (2Mx4N), per-wave out 128x64.  C = A[M,K] * Bt[N,K]^T.
// EPI: 2 = silu-pair (interleaved gate/up cols -> bf16, ldc = out width)
//      3 = f32 out.
// Requires M%256==0, N%256==0, K%32==0, K/32 even and >=4, (gX*gY)%8==0.
// ---------------------------------------------------------------------------
template <int EPI>
__global__ __launch_bounds__(512, 2) void gemm256_k(
    const u16* __restrict__ A, int lda,
    const u16* __restrict__ Bt, int ldb,
    void* __restrict__ C, int ldc, int K)
{
  __shared__ __align__(16) u16 Bsm[4][256 * 32];   // 64 KiB total

  const int tid  = threadIdx.x;
  const int lane = tid & 63;
  const int lrow = lane & 15;
  const int g    = lane >> 4;
  const int wid  = tid >> 6;
  const int wm   = wid >> 2, wn = wid & 3;

  int flat = blockIdx.y * gridDim.x + blockIdx.x;
  const int cpx = (gridDim.x * gridDim.y) >> 3;
  flat = (flat & 7) * cpx + (flat >> 3);
  const int bx = flat % gridDim.x;
  const int by = flat / gridDim.x;

  // B staging sources (pre-swizzled involution, as proven since round 3)
  const int r0   = tid >> 2, pp = tid & 3;
  const int row1 = 128 + (tid >> 2);
  const int p0 = pp ^ ((r0 ^ (r0 >> 2)) & 3);
  const int p1 = pp ^ ((row1 ^ (row1 >> 2)) & 3);
  const u16* bS0 = Bt + (size_t)(by * 256 + r0)   * ldb + p0 * 8;
  const u16* bS1 = Bt + (size_t)(by * 256 + row1) * ldb + p1 * 8;
  const int lB0 = tid * 16, lB1 = (512 + tid) * 16;

  int bOff[4];
  #pragma unroll
  for (int fn = 0; fn < 4; fn++) {
    const int r = wn * 64 + fn * 16 + lrow;
    bOff[fn] = r * 32 + (g ^ ((r ^ (r >> 2)) & 3)) * 8;
  }

  // A direct-load row pointers (per fragment)
  const u16* aP[8];
  #pragma unroll
  for (int fm = 0; fm < 8; fm++) {
    const int r = bx * 256 + wm * 128 + fm * 16 + lrow;
    aP[fm] = A + (size_t)r * lda + g * 8;
  }

  f32x4 acc[8][4] = {};
  const int ntk = K / 32;   // even, >= 4

  // --- prologue ---------------------------------------------------------
  gload16(bS0 + 0,  (char*)Bsm[0] + lB0);
  gload16(bS1 + 0,  (char*)Bsm[0] + lB1);
  gload16(bS0 + 32, (char*)Bsm[1] + lB0);
  gload16(bS1 + 32, (char*)Bsm[1] + lB1);
  __builtin_amdgcn_sched_barrier(0);
  bf16x8 aE[8], aO[8];
  #pragma unroll
  for (int i = 0; i < 8; i++) aE[i] = ld128(aP[i]);        // A(0)
  __builtin_amdgcn_sched_barrier(0);
  gload16(bS0 + 64, (char*)Bsm[2] + lB0);
  gload16(bS1 + 64, (char*)Bsm[2] + lB1);
  waitvm<12>();   // B(0) landed (B(1):2 + A(0):8 + B(2):2 = 12 younger)
  __builtin_amdgcn_s_barrier();

  // --- main loop: body(t) with aCur/aNxt register double-buffer ----------
#define GBODY(T, ACUR, ANXT, LOADA, STGB, VMW)                                  \
  {                                                                             \
    const int t_ = (T);                                                         \
    bf16x8 bf[4];                                                               \
    _Pragma("unroll") for (int i = 0; i < 4; i++)                               \
      bf[i] = ld128(&Bsm[t_ & 3][bOff[i]]);                                     \
    if (LOADA) {                                                                \
      _Pragma("unroll") for (int i = 0; i < 8; i++)                             \
        ANXT[i] = ld128(aP[i] + (long)(t_ + 1) * 32);                           \
    }                                                                           \
    if (STGB) {                                                                 \
      const long kt = (long)(t_ + 2) * 32;                                      \
      gload16(bS0 + kt, (char*)Bsm[(t_ + 2) & 3] + lB0);                        \
      gload16(bS1 + kt, (char*)Bsm[(t_ + 2) & 3] + lB1);                        \
    }                                                                           \
    asm volatile("s_waitcnt lgkmcnt(0)" ::: "memory");                          \
    __builtin_amdgcn_sched_barrier(0);                                          \
    __builtin_amdgcn_s_barrier();                                               \
    __builtin_amdgcn_s_setprio(1);                                              \
    _Pragma("unroll") for (int m = 0; m < 8; m++)                               \
      _Pragma("unroll") for (int n = 0; n < 4; n++)                             \
        acc[m][n] = __builtin_amdgcn_mfma_f32_16x16x32_bf16(ACUR[m], bf[n], acc[m][n], 0, 0, 0); \
    __builtin_amdgcn_s_setprio(0);                                              \
    VMW;                                                                        \
    __builtin_amdgcn_sched_barrier(0);                                          \
    __builtin_amdgcn_s_barrier();                                               \
  }

  for (int t = 0; t + 2 < ntk; t += 2) {
    GBODY(t,     aE, aO, true, true,              waitvm<10>());
    GBODY(t + 1, aO, aE, true, (t + 3 < ntk),     waitvm<10>());
  }
  // peeled tail: t = ntk-2 (even -> aE current), t = ntk-1 (aO current)
  GBODY(ntk - 2, aE, aO, true,  false, waitvm<8>());
  GBODY(ntk - 1, aO, aE, false, false, (void)0);
#undef GBODY

  if (EPI == 2) {
    #pragma unroll
    for (int fm = 0; fm < 8; fm++) {
      #pragma unroll
      for (int fp = 0; fp < 2; fp++) {
        #pragma unroll
        for (int r = 0; r < 4; r++) {
          const size_t row = bx * 256 + wm * 128 + fm * 16 + g * 4 + r;
          const int nb = by * 256 + wn * 64 + fp * 32;
          const int oc = (nb >> 5) * 16 + lrow;
          const float gg = acc[fm][2 * fp][r];
          const float uu = acc[fm][2 * fp + 1][r];
          ((u16*)C)[row * ldc + oc] = f2b(gg / (1.f + __expf(-gg)) * uu);
        }
      }
    }
  } else {
    #pragma unroll
    for (int fm = 0; fm < 8; fm++) {
      #pragma unroll
      for (int fn = 0; fn < 4; fn++) {
        #pragma unroll
        for (int r = 0; r < 4; r++) {
          const size_t row = bx * 256 + wm * 128 + fm * 16 + g * 4 + r;
          const size_t col = by * 256 + wn * 64 + fn * 16 + lrow;
          ((float*)C)[row * ldc + col] = acc[fm][fn][r];
        }
      }
    }
  }
}

// ---------------------------------------------------------------------------
// Small-tile GEMM, 4-slot counted-vmcnt ring (round-8 version, proven).
// EPI: 0 bf16 out; 4 fused QKV-RoPE epilogue (WC must be 64 = one head).
// Requires K/32 >= 4.
// ---------------------------------------------------------------------------
template <int BM, int BN, int WM, int WN, int EPI>
__global__ __launch_bounds__(256) void gemm_k(
    const u16* __restrict__ A, int lda,
    const u16* __restrict__ Bt, int ldb,
    void* __restrict__ C, int ldc,
    const float2* __restrict__ tab, int K)
{
  constexpr int LA = (BM * 4) / 256;
  constexpr int LB = (BN * 4) / 256;
  constexpr int LT = LA + LB;

  __shared__ __align__(16) u16 Asm[4][BM * 32];
  __shared__ __align__(16) u16 Bsm[4][BN * 32];

  const int tid  = threadIdx.x;
  const int lane = tid & 63;
  const int lrow = lane & 15;
  const int kb   = lane >> 4;
  const int w    = tid >> 6;
  const int wm   = w / WN, wn = w % WN;
  constexpr int WR = BM / WM, WC = BN / WN;
  constexpr int FM = WR / 16, FN = WC / 16;

  const u16* aS[LA];
  const u16* bS[LB];
  #pragma unroll
  for (int i = 0; i < LA; i++) {
    const int row = (i * 256 + tid) >> 2, pp = tid & 3;
    const int p = pp ^ ((row ^ (row >> 2)) & 3);
    aS[i] = A + (size_t)(blockIdx.x * BM + row) * lda + p * 8;
  }
  #pragma unroll
  for (int i = 0; i < LB; i++) {
    const int row = (i * 256 + tid) >> 2, pp = tid & 3;
    const int p = pp ^ ((row ^ (row >> 2)) & 3);
    bS[i] = Bt + (size_t)(blockIdx.y * BN + row) * ldb + p * 8;
  }

  int aOff[FM], bOff[FN];
  #pragma unroll
  for (int fm = 0; fm < FM; fm++) {
    const int r = wm * WR + fm * 16 + lrow;
    aOff[fm] = r * 32 + (kb ^ ((r ^ (r >> 2)) & 3)) * 8;
  }
  #pragma unroll
  for (int fn = 0; fn < FN; fn++) {
    const int r = wn * WC + fn * 16 + lrow;
    bOff[fn] = r * 32 + (kb ^ ((r ^ (r >> 2)) & 3)) * 8;
  }

  f32x4 acc[FM][FN] = {};
  const int ntk = K / 32;

  #pragma unroll
  for (int ts = 0; ts < 3; ts++) {
    #pragma unroll
    for (int i = 0; i < LA; i++)
      gload16(aS[i] + ts * 32, (char*)Asm[ts] + (i * 256 + tid) * 16);
    #pragma unroll
    for (int i = 0; i < LB; i++)
      gload16(bS[i] + ts * 32, (char*)Bsm[ts] + (i * 256 + tid) * 16);
  }
  waitvm<2 * LT>();
  __builtin_amdgcn_s_barrier();

#define SKTILE(VMW, STG)                                                        \
  {                                                                             \
    const int rs = t & 3, ss = (t + 3) & 3;                                     \
    const long kt = (long)(t + 3) * 32;                                         \
    bf16x8 af[FM], bf[FN];                                                      \
    _Pragma("unroll") for (int i = 0; i < FN; i++) bf[i] = ld128(&Bsm[rs][bOff[i]]); \
    _Pragma("unroll") for (int i = 0; i < FM; i++) af[i] = ld128(&Asm[rs][aOff[i]]); \
    if (STG) {                                                                  \
      _Pragma("unroll") for (int i = 0; i < LA; i++)                            \
        gload16(aS[i] + kt, (char*)Asm[ss] + (i * 256 + tid) * 16);             \
      _Pragma("unroll") for (int i = 0; i < LB; i++)                            \
        gload16(bS[i] + kt, (char*)Bsm[ss] + (i * 256 + tid) * 16);             \
    }                                                                           \
    __builtin_amdgcn_s_barrier();                                               \
    asm volatile("s_waitcnt lgkmcnt(0)" ::: "memory");                          \
    __builtin_amdgcn_sched_barrier(0);                                          \
    __builtin_amdgcn_s_setprio(1);                                              \
    _Pragma("unroll") for (int m = 0; m < FM; m++)                              \
      _Pragma("unroll") for (int n = 0; n < FN; n++)                            \
        acc[m][n] = __builtin_amdgcn_mfma_f32_16x16x32_bf16(af[m], bf[n], acc[m][n], 0, 0, 0); \
    __builtin_amdgcn_s_setprio(0);                                              \
    VMW;                                                                        \
    __builtin_amdgcn_sched_barrier(0);                                          \
    __builtin_amdgcn_s_barrier();                                               \
  }

  {
    int t = 0;
    for (; t < ntk - 3; ++t) SKTILE(waitvm<2 * LT>(), true);
    SKTILE(waitvm<LT>(), false); ++t;
    SKTILE(waitvm<0>(), false); ++t;
    SKTILE((void)0, false);
  }
#undef SKTILE

  if (EPI == 4) {
    const int colb = blockIdx.y * BN + wn * WC;
    const int head = colb >> 6;                          // 0..31
    const float qs = (head < 16) ? 0.125f : 1.0f;
    #pragma unroll
    for (int fm = 0; fm < FM; fm++) {
      #pragma unroll
      for (int r = 0; r < 4; r++) {
        const int row = blockIdx.x * BM + wm * WR + fm * 16 + kb * 4 + r;
        if (head >= 24) {   // v heads: no rope
          #pragma unroll
          for (int fn = 0; fn < FN; fn++)
            ((u16*)C)[row * ldc + colb + fn * 16 + lrow] = f2b(acc[fm][fn][r]);
        } else {
          const int s = row & (S - 1);
          #pragma unroll
          for (int fp = 0; fp < 2; fp++) {
            const int d = fp * 16 + lrow;               // 0..31
            const float2 cs = tab[s * 32 + d];
            const float x1 = acc[fm][fp][r];
            const float x2 = acc[fm][fp + 2][r];
            ((u16*)C)[row * ldc + colb + d]      = f2b((x1 * cs.x - x2 * cs.y) * qs);
            ((u16*)C)[row * ldc + colb + d + 32] = f2b((x2 * cs.x + x1 * cs.y) * qs);
          }
        }
      }
    }
  } else {
    #pragma unroll
    for (int fm = 0; fm < FM; fm++) {
      #pragma unroll
      for (int fn = 0; fn < FN; fn++) {
        #pragma unroll
        for (int r = 0; r < 4; r++) {
          const int row = blockIdx.x * BM + wm * WR + fm * 16 + kb * 4 + r;
          const int col = blockIdx.y * BN + wn * WC + fn * 16 + lrow;
          ((u16*)C)[row * ldc + col] = f2b(acc[fm][fn][r]);
        }
      }
    }
  }
}

// ---------------------------------------------------------------------------
// Layer-batched transpose-convert: W[z][K][N] f32 -> WT[z][rowmap(n)][K] bf16
// rmode: 0 identity; 1 gate-interleave; 2 up-interleave.
// ---------------------------------------------------------------------------
__global__ __launch_bounds__(256) void transpose_k(
    const float* __restrict__ W, u16* __restrict__ WT, int K, int N, int rmode,
    size_t wstride, size_t tstride)
{
  __shared__ float t[32][33];
  const float* Wp = W + (size_t)blockIdx.z * wstride;
  u16* WTp = WT + (size_t)blockIdx.z * tstride;
  const int k0 = blockIdx.x * 32, n0 = blockIdx.y * 32;
  const int tx = threadIdx.x & 31, ty = threadIdx.x >> 5;
  #pragma unroll
  for (int i = 0; i < 32; i += 8)
    t[ty + i][tx] = Wp[(size_t)(k0 + ty + i) * N + (n0 + tx)];
  __syncthreads();
  #pragma unroll
  for (int i = 0; i < 32; i += 8) {
    const int n = n0 + ty + i;
    const int orow = (rmode == 0) ? n : ((n >> 4) * 32 + (n & 15) + ((rmode == 2) ? 16 : 0));
    WTp[(size_t)orow * K + (k0 + tx)] = f2b(t[tx][ty + i]);
  }
}

// ---------------------------------------------------------------------------
__global__ __launch_bounds__(256) void embed_k(
    const int* __restrict__ ids, const float* __restrict__ E, float* __restrict__ h)
{
  const int t = blockIdx.x;
  const int id = ids[t];
  ((float4*)(h + t * H))[threadIdx.x] = ((const float4*)(E + (size_t)id * H))[threadIdx.x];
}

// ---------------------------------------------------------------------------
__global__ __launch_bounds__(256) void rmsnorm_k(
    const float* __restrict__ h, const float* __restrict__ w, u16* __restrict__ x)
{
  const int row = blockIdx.x;
  const float4 hv = ((const float4*)(h + row * H))[threadIdx.x];
  float s = hv.x * hv.x + hv.y * hv.y + hv.z * hv.z + hv.w * hv.w;
  #pragma unroll
  for (int off = 32; off; off >>= 1) s += __shfl_xor(s, off, 64);
  __shared__ float red[4];
  if ((threadIdx.x & 63) == 0) red[threadIdx.x >> 6] = s;
  __syncthreads();
  s = red[0] + red[1] + red[2] + red[3];
  const float scale = rsqrtf(s * (1.f / H) + 1e-6f);
  const float4 wv = ((const float4*)w)[threadIdx.x];
  ushort4 ov;
  ov.x = f2b(hv.x * scale * wv.x);
  ov.y = f2b(hv.y * scale * wv.y);
  ov.z = f2b(hv.z * scale * wv.z);
  ov.w = f2b(hv.w * scale * wv.w);
  ((ushort4*)(x + row * H))[threadIdx.x] = ov;
}

// ---------------------------------------------------------------------------
// Fused residual add + RMSNorm: h += dl (bf16 delta); x = rms(h)*w.
// ---------------------------------------------------------------------------
__global__ __launch_bounds__(256) void addnorm_k(
    float* __restrict__ h, const u16* __restrict__ dl,
    const float* __restrict__ w, u16* __restrict__ x)
{
  const int row = blockIdx.x;
  float4 hv = ((const float4*)(h + row * H))[threadIdx.x];
  const ushort4 dv = ((const ushort4*)(dl + row * H))[threadIdx.x];
  hv.x += b2f(dv.x); hv.y += b2f(dv.y); hv.z += b2f(dv.z); hv.w += b2f(dv.w);
  ((float4*)(h + row * H))[threadIdx.x] = hv;
  float s = hv.x * hv.x + hv.y * hv.y + hv.z * hv.z + hv.w * hv.w;
  #pragma unroll
  for (int off = 32; off; off >>= 1) s += __shfl_xor(s, off, 64);
  __shared__ float red[4];
  if ((threadIdx.x & 63) == 0) red[threadIdx.x >> 6] = s;
  __syncthreads();
  s = red[0] + red[1] + red[2] + red[3];
  const float scale = rsqrtf(s * (1.f / H) + 1e-6f);
  const float4 wv = ((const float4*)w)[threadIdx.x];
  ushort4 ov;
  ov.x = f2b(hv.x * scale * wv.x);
  ov.y = f2b(hv.y * scale * wv.y);
  ov.z = f2b(hv.z * scale * wv.z);
  ov.w = f2b(hv.w * scale * wv.w);
  ((ushort4*)(x + row * H))[threadIdx.x] = ov;
}

// ---------------------------------------------------------------------------
__global__ __launch_bounds__(256) void ropetab_k(float2* __restrict__ tab)
{
  const int idx = blockIdx.x * 256 + threadIdx.x;
  const int s = idx >> 5, d = idx & 31;
  const float ang = s * powf(10000.f, -(2.f * d) / 64.f);
  float sn, cs;
  sincosf(ang, &sn, &cs);
  tab[idx] = make_float2(cs, sn);
}

// ---------------------------------------------------------------------------
// Flash attention v2.  512 blocks (one per (q-tile, bh)), 256 thr = 4 waves.
// XCD-aware bh grouping; long q-tiles first; defer-max rescale skip.
// ---------------------------------------------------------------------------
__global__ __launch_bounds__(256) void fattn_k(
    const u16* __restrict__ qkv, u16* __restrict__ o)
{
  __shared__ __align__(16) u16 Ks[64 * 64];
  __shared__ __align__(16) u16 Vt[64 * 72];
  __shared__ __align__(16) u16 Pw[4][16 * 64];

  const int tid  = threadIdx.x;
  const int lane = tid & 63;
  const int lrow = lane & 15;
  const int g    = lane >> 4;
  const int w    = tid >> 6;

  const int bid = blockIdx.x;                 // 0..511
  const int j   = bid >> 3;
  const int bh  = (bid & 7) * 4 + (j & 3);    // 0..31
  const int bx  = 15 - (j >> 2);              // long q-tiles first
  const int b = bh >> 4, hh = bh & 15, kh = hh >> 1;
  const int q0 = bx * 64;

  bf16x8 aq[2];
  {
    const int qrow = q0 + w * 16 + lrow;
    const u16* qp = qkv + (size_t)(b * S + qrow) * QKVW + hh * 64 + g * 8;
    aq[0] = *reinterpret_cast<const bf16x8*>(qp);
    aq[1] = *reinterpret_cast<const bf16x8*>(qp + 32);
  }

  f32x4 oacc[4] = {};
  float mrow[4], lsum[4];
  #pragma unroll
  for (int r = 0; r < 4; r++) { mrow[r] = -1e30f; lsum[r] = 0.f; }

  const int nt = bx + 1;
  for (int t = 0; t < nt; t++) {
    const int kv0 = t * 64;
    __syncthreads();   // prev-iter LDS reads complete

    #pragma unroll
    for (int i = 0; i < 2; i++) {
      const int c = i * 256 + tid;
      const int r = c >> 3, p = c & 7;
      gload16(qkv + (size_t)(b * S + kv0 + r) * QKVW + 1024 + kh * 64 + ((p ^ (r & 7)) * 8),
              (char*)Ks + c * 16);
    }
    u16x8 vreg[2];
    #pragma unroll
    for (int i = 0; i < 2; i++) {
      const int c = i * 256 + tid;
      const int k = c >> 3, dch = c & 7;
      vreg[i] = *reinterpret_cast<const u16x8*>(
          qkv + (size_t)(b * S + kv0 + k) * QKVW + 1536 + kh * 64 + dch * 8);
    }
    #pragma unroll
    for (int i = 0; i < 2; i++) {
      const int c = i * 256 + tid;
      const int k = c >> 3, d0 = (c & 7) * 8;
      #pragma unroll
      for (int j2 = 0; j2 < 8; j2++) {
        const int d = d0 + j2;
        Vt[d * 72 + (((k >> 3) ^ (d >> 3)) * 8) + (k & 7)] = vreg[i][j2];
      }
    }
    __syncthreads();

    f32x4 sacc[4] = {};
    #pragma unroll
    for (int n = 0; n < 4; n++) {
      const int row = n * 16 + lrow;
      #pragma unroll
      for (int k2 = 0; k2 < 2; k2++) {
        const bf16x8 bk = *reinterpret_cast<const bf16x8*>(
            Ks + row * 64 + (((k2 * 4 + g) ^ (row & 7)) * 8));
        sacc[n] = __builtin_amdgcn_mfma_f32_16x16x32_bf16(aq[k2], bk, sacc[n], 0, 0, 0);
      }
    }

    float rmv[4];
    #pragma unroll
    for (int r = 0; r < 4; r++) {
      const int qglob = q0 + w * 16 + g * 4 + r;
      float rm = -1e30f;
      #pragma unroll
      for (int n = 0; n < 4; n++) {
        const int kg = kv0 + n * 16 + lrow;
        if (kg > qglob) sacc[n][r] = -1e30f;
        rm = fmaxf(rm, sacc[n][r]);
      }
      #pragma unroll
      for (int mk = 1; mk < 16; mk <<= 1) rm = fmaxf(rm, __shfl_xor(rm, mk, 64));
      rmv[r] = rm;
    }

    int need = 0;
    #pragma unroll
    for (int r = 0; r < 4; r++) need |= (rmv[r] > mrow[r] + 8.f) ? 1 : 0;
    if (__any(need)) {
      #pragma unroll
      for (int r = 0; r < 4; r++) {
        const float mnew  = fmaxf(mrow[r], rmv[r]);
        const float scale = __expf(mrow[r] - mnew);
        mrow[r] = mnew;
        lsum[r] *= scale;
        #pragma unroll
        for (int dt = 0; dt < 4; dt++) oacc[dt][r] *= scale;
      }
    }

    #pragma unroll
    for (int r = 0; r < 4; r++) {
      float rs = 0.f;
      u16 pb[4];
      #pragma unroll
      for (int n = 0; n < 4; n++) {
        const float p = __expf(sacc[n][r] - mrow[r]);
        rs += p;
        pb[n] = f2b(p);
      }
      #pragma unroll
      for (int mk = 1; mk < 16; mk <<= 1) rs += __shfl_xor(rs, mk, 64);
      lsum[r] += rs;
      const int ql = g * 4 + r;
      #pragma unroll
      for (int n = 0; n < 4; n++) {
        const int k = n * 16 + lrow;
        Pw[w][ql * 64 + (((k >> 3) ^ (ql & 7)) * 8) + (k & 7)] = pb[n];
      }
    }

    #pragma unroll
    for (int k2 = 0; k2 < 2; k2++) {
      const bf16x8 pa = *reinterpret_cast<const bf16x8*>(
          &Pw[w][lrow * 64 + (((k2 * 4 + g) ^ (lrow & 7)) * 8)]);
      #pragma unroll
      for (int dt = 0; dt < 4; dt++) {
        const int d = dt * 16 + lrow;
        const bf16x8 vb = *reinterpret_cast<const bf16x8*>(
            &Vt[d * 72 + (((k2 * 4 + g) ^ (d >> 3)) * 8)]);
        oacc[dt] = __builtin_amdgcn_mfma_f32_16x16x32_bf16(pa, vb, oacc[dt], 0, 0, 0);
      }
    }
  }

  #pragma unroll
  for (int dt = 0; dt < 4; dt++) {
    #pragma unroll
    for (int r = 0; r < 4; r++) {
      const int qrow = q0 + w * 16 + g * 4 + r;
      o[(size_t)(b * S + qrow) * H + hh * 64 + dt * 16 + lrow] =
          f2b(oacc[dt][r] / lsum[r]);
    }
  }
}

// ---------------------------------------------------------------------------
extern "C" void kernel_launch(void* const* d_in, const int* in_sizes, int n_in,
                              void* d_out, int out_size, void* d_ws, size_t ws_size,
                              hipStream_t stream)
{
  const int*   ids  = (const int*)d_in[0];
  const float* EW   = (const float*)d_in[1];
  const float* Wq   = (const float*)d_in[2];
  const float* Wk   = (const float*)d_in[3];
  const float* Wv   = (const float*)d_in[4];
  const float* Wo   = (const float*)d_in[5];
  const float* Wg   = (const float*)d_in[6];
  const float* Wu   = (const float*)d_in[7];
  const float* Wd   = (const float*)d_in[8];
  const float* ln1  = (const float*)d_in[9];
  const float* ln2  = (const float*)d_in[10];
  const float* nw   = (const float*)d_in[11];
  const float* lmw  = (const float*)d_in[12];
  float* out = (float*)d_out;

  const size_t MB = 1u << 20;
  char* ws = (char*)d_ws;
  float*  h   = (float*)(ws);                  // 8 MiB  [NT][H] f32
  u16*    x   = (u16*)(ws + 8 * MB);           // 4 MiB  [NT][H]
  u16*    qkv = (u16*)(ws + 12 * MB);          // 8 MiB  [NT][2048]
  u16*    o   = (u16*)(ws + 20 * MB);          // 4 MiB  [NT][H]
  u16*    dl  = (u16*)(ws + 24 * MB);          // 4 MiB  [NT][H]
  u16*    ub  = (u16*)(ws + 28 * MB);          // 16 MiB [NT][4096]
  float2* tab = (float2*)(ws + 44 * MB);       // 256 KiB
  char*   wb  = ws + 45 * MB;

  const size_t sqkv = (size_t)QKVW * H;        // elems per layer (4 MiB)
  const size_t swo  = (size_t)H * H;           // 2 MiB
  const size_t sgu  = (size_t)2 * FF * H;      // 16 MiB
  const size_t swd  = (size_t)H * FF;          // 8 MiB

  const bool full = ws_size >= 349 * MB;
  if (!full && ws_size < 108 * MB) return;     // cannot run; fail loudly

  u16 *wqkvT, *woT, *wguT, *wdT, *lmT;
  if (full) {
    wqkvT = (u16*)wb;                          // 32 MiB
    woT   = wqkvT + NL * sqkv;                 // 16 MiB
    wguT  = woT + NL * swo;                    // 128 MiB
    wdT   = wguT + NL * sgu;                   // 64 MiB
    lmT   = wdT + NL * swd;                    // 62.5 MiB
  } else {
    wqkvT = (u16*)wb;
    woT   = wqkvT + sqkv;
    wguT  = woT + swo;
    wdT   = wguT + sgu;
    lmT   = (u16*)wb;                          // reused after the layer loop
  }

  auto xpose = [&](int l0, int lz, bool dense) {
    const size_t tq = dense ? sqkv : 0, to = dense ? swo : 0;
    const size_t tg = dense ? sgu : 0,  td = dense ? swd : 0;
    transpose_k<<<dim3(H / 32, H / 32, lz), 256, 0, stream>>>(
        Wq + (size_t)l0 * H * H, wqkvT + (size_t)l0 * tq, H, H, 0, (size_t)H * H, tq);
    transpose_k<<<dim3(H / 32, 512 / 32, lz), 256, 0, stream>>>(
        Wk + (size_t)l0 * H * 512, wqkvT + (size_t)l0 * tq + (size_t)1024 * H, H, 512, 0,
        (size_t)H * 512, tq);
    transpose_k<<<dim3(H / 32, 512 / 32, lz), 256, 0, stream>>>(
        Wv + (size_t)l0 * H * 512, wqkvT + (size_t)l0 * tq + (size_t)1536 * H, H, 512, 0,
        (size_t)H * 512, tq);
    transpose_k<<<dim3(H / 32, H / 32, lz), 256, 0, stream>>>(
        Wo + (size_t)l0 * H * H, woT + (size_t)l0 * to, H, H, 0, (size_t)H * H, to);
    transpose_k<<<dim3(H / 32, FF / 32, lz), 256, 0, stream>>>(
        Wg + (size_t)l0 * H * FF, wguT + (size_t)l0 * tg, H, FF, 1, (size_t)H * FF, tg);
    transpose_k<<<dim3(H / 32, FF / 32, lz), 256, 0, stream>>>(
        Wu + (size_t)l0 * H * FF, wguT + (size_t)l0 * tg, H, FF, 2, (size_t)H * FF, tg);
    transpose_k<<<dim3(FF / 32, H / 32, lz), 256, 0, stream>>>(
        Wd + (size_t)l0 * FF * H, wdT + (size_t)l0 * td, FF, H, 0, (size_t)FF * H, td);
  };

  embed_k<<<NT, 256, 0, stream>>>(ids, EW, h);
  ropetab_k<<<(S * 32) / 256, 256, 0, stream>>>(tab);

  if (full) {
    xpose(0, NL, true);
    transpose_k<<<dim3(H / 32, V / 32, 1), 256, 0, stream>>>(lmw, lmT, H, V, 0, 0, 0);
  }

  // x for layer 0
  rmsnorm_k<<<NT, 256, 0, stream>>>(h, ln1, x);

  for (int l = 0; l < NL; l++) {
    if (!full) xpose(l, 1, false);
    u16* pq = wqkvT + (full ? (size_t)l * sqkv : 0);
    u16* po = woT   + (full ? (size_t)l * swo  : 0);
    u16* pg = wguT  + (full ? (size_t)l * sgu  : 0);
    u16* pd = wdT   + (full ? (size_t)l * swd  : 0);

    // ---- attention ----
    gemm_k<64, 128, 2, 2, 4><<<dim3(NT / 64, QKVW / 128), 256, 0, stream>>>(
        x, H, pq, H, qkv, QKVW, tab, H);
    fattn_k<<<dim3(512), 256, 0, stream>>>(qkv, o);
    gemm_k<64, 64, 2, 2, 0><<<dim3(NT / 64, H / 64), 256, 0, stream>>>(
        o, H, po, H, dl, H, nullptr, H);
    addnorm_k<<<NT, 256, 0, stream>>>(h, dl, ln2 + l * H, x);

    // ---- MLP ----
    gemm256_k<2><<<dim3(NT / 256, (2 * FF) / 256), 512, 0, stream>>>(
        x, H, pg, H, ub, FF, H);
    gemm_k<64, 64, 2, 2, 0><<<dim3(NT / 64, H / 64), 256, 0, stream>>>(
        ub, FF, pd, FF, dl, H, nullptr, FF);
    const float* nxt = (l + 1 < NL) ? (ln1 + (l + 1) * H) : nw;
    addnorm_k<<<NT, 256, 0, stream>>>(h, dl, nxt, x);
  }

  if (!full)
    transpose_k<<<dim3(H / 32, V / 32, 1), 256, 0, stream>>>(lmw, lmT, H, V, 0, 0, 0);
  gemm256_k<3><<<dim3(NT / 256, V / 256), 512, 0, stream>>>(
      x, H, lmT, H, out, V, H);
}

// Round 12
// 1809.488 us; speedup vs baseline: 1.2281x; 1.2281x over previous
//
#include <hip/hip_runtime.h>

// ---------------------------------------------------------------------------
// Qwen3-style 8-layer transformer forward on MI355X (gfx950).
// Round 12: byte-for-byte revert to the round-8 kernel (best measured:
// 1811 us).  gemm256_k = 4-slot depth-3 counted-vmcnt ring, 2-phase body;
// gemm_k = same ring, single-phase; fattn v2; fused RoPE/SiLU/addnorm.
// Rounds 9/10/11 (2-slot ring, 1-phase 4-slot, A-direct) all regressed and
// are abandoned.
// ---------------------------------------------------------------------------

typedef unsigned short u16;
typedef __bf16  bf16x8 __attribute__((ext_vector_type(8)));   // 4 VGPRs
typedef unsigned short u16x8 __attribute__((ext_vector_type(8)));
typedef float   f32x4  __attribute__((ext_vector_type(4)));

#define DEV static __device__ __forceinline__

constexpr int NB  = 2;
constexpr int S   = 1024;
constexpr int NT  = NB * S;
constexpr int H   = 1024;
constexpr int NH  = 16;
constexpr int NKV = 8;
constexpr int HD  = 64;
constexpr int NL  = 8;
constexpr int FF  = 4096;
constexpr int V   = 32000;
constexpr int QKVW = 2048;

DEV float b2f(u16 x) { return __uint_as_float(((unsigned)x) << 16); }
DEV u16   f2b(float f) {
  unsigned i = __float_as_uint(f);
  return (u16)((i + 0x7fffu + ((i >> 16) & 1u)) >> 16);   // RNE
}

DEV void gload16(const void* g, void* l) {
  __builtin_amdgcn_global_load_lds(
      (const __attribute__((address_space(1))) void*)g,
      (__attribute__((address_space(3))) void*)l, 16, 0, 0);
}

DEV bf16x8 ld128(const u16* p) { return *reinterpret_cast<const bf16x8*>(p); }

template <int N> DEV void waitvm() {
  if constexpr (N == 0)      asm volatile("s_waitcnt vmcnt(0)" ::: "memory");
  else if constexpr (N == 2) asm volatile("s_waitcnt vmcnt(2)" ::: "memory");
  else if constexpr (N == 3) asm volatile("s_waitcnt vmcnt(3)" ::: "memory");
  else if constexpr (N == 4) asm volatile("s_waitcnt vmcnt(4)" ::: "memory");
  else if constexpr (N == 6) asm volatile("s_waitcnt vmcnt(6)" ::: "memory");
  else                       asm volatile("s_waitcnt vmcnt(8)" ::: "memory");
}

// ---------------------------------------------------------------------------
// 256x256-tile GEMM, BK=32, 4-slot LDS ring (depth-3 prefetch, counted
// vmcnt(8)), 512 thr = 8 waves (2Mx4N).  C = A[M,K] * Bt[N,K]^T.
// EPI: 2 = silu-pair (interleaved gate/up cols -> bf16, ldc = out width)
//      3 = f32 out.
// Requires M%256==0, N%256==0, K%32==0, K/32>=4, (gridX*gridY)%8==0.
// ---------------------------------------------------------------------------
template <int EPI>
__global__ __launch_bounds__(512, 2) void gemm256_k(
    const u16* __restrict__ A, int lda,
    const u16* __restrict__ Bt, int ldb,
    void* __restrict__ C, int ldc, int K)
{
  __shared__ __align__(16) u16 Asm[4][256 * 32];   // 64 KiB
  __shared__ __align__(16) u16 Bsm[4][256 * 32];   // 64 KiB

  const int tid  = threadIdx.x;
  const int lane = tid & 63;
  const int lrow = lane & 15;
  const int g    = lane >> 4;
  const int wid  = tid >> 6;
  const int wm   = wid >> 2, wn = wid & 3;

  int flat = blockIdx.y * gridDim.x + blockIdx.x;
  const int cpx = (gridDim.x * gridDim.y) >> 3;
  flat = (flat & 7) * cpx + (flat >> 3);
  const int bx = flat % gridDim.x;
  const int by = flat / gridDim.x;

  const int r0   = tid >> 2, pp = tid & 3;
  const int row1 = 128 + (tid >> 2);
  const int p0 = pp ^ ((r0 ^ (r0 >> 2)) & 3);
  const int p1 = pp ^ ((row1 ^ (row1 >> 2)) & 3);
  const u16* aS0 = A  + (size_t)(bx * 256 + r0)   * lda + p0 * 8;
  const u16* aS1 = A  + (size_t)(bx * 256 + row1) * lda + p1 * 8;
  const u16* bS0 = Bt + (size_t)(by * 256 + r0)   * ldb + p0 * 8;
  const u16* bS1 = Bt + (size_t)(by * 256 + row1) * ldb + p1 * 8;
  const int aB0 = tid * 16, aB1 = (512 + tid) * 16;

  int aOff[8], bOff[4];
  #pragma unroll
  for (int fm = 0; fm < 8; fm++) {
    const int r = wm * 128 + fm * 16 + lrow;
    aOff[fm] = r * 32 + (g ^ ((r ^ (r >> 2)) & 3)) * 8;
  }
  #pragma unroll
  for (int fn = 0; fn < 4; fn++) {
    const int r = wn * 64 + fn * 16 + lrow;
    bOff[fn] = r * 32 + (g ^ ((r ^ (r >> 2)) & 3)) * 8;
  }

  f32x4 acc[8][4] = {};
  const int ntk = K / 32;

  #pragma unroll
  for (int ts = 0; ts < 3; ts++) {
    const long kt = (long)ts * 32;
    gload16(aS0 + kt, (char*)Asm[ts] + aB0);
    gload16(bS0 + kt, (char*)Bsm[ts] + aB0);
    gload16(aS1 + kt, (char*)Asm[ts] + aB1);
    gload16(bS1 + kt, (char*)Bsm[ts] + aB1);
  }
  asm volatile("s_waitcnt vmcnt(8)" ::: "memory");
  __builtin_amdgcn_s_barrier();

#define KTILE(VMW, STG)                                                         \
  {                                                                             \
    const int rs = t & 3, ss = (t + 3) & 3;                                     \
    const long kt = (long)(t + 3) * 32;                                         \
    bf16x8 af[4], bf[4];                                                        \
    _Pragma("unroll") for (int i = 0; i < 4; i++) bf[i] = ld128(&Bsm[rs][bOff[i]]); \
    _Pragma("unroll") for (int i = 0; i < 4; i++) af[i] = ld128(&Asm[rs][aOff[i]]); \
    if (STG) { gload16(aS0 + kt, (char*)Asm[ss] + aB0);                         \
               gload16(bS0 + kt, (char*)Bsm[ss] + aB0); }                       \
    __builtin_amdgcn_s_barrier();                                               \
    asm volatile("s_waitcnt lgkmcnt(0)" ::: "memory");                          \
    __builtin_amdgcn_sched_barrier(0);                                          \
    __builtin_amdgcn_s_setprio(1);                                              \
    _Pragma("unroll") for (int m = 0; m < 4; m++)                               \
      _Pragma("unroll") for (int n = 0; n < 4; n++)                             \
        acc[m][n] = __builtin_amdgcn_mfma_f32_16x16x32_bf16(af[m], bf[n], acc[m][n], 0, 0, 0); \
    __builtin_amdgcn_s_setprio(0);                                              \
    __builtin_amdgcn_s_barrier();                                               \
    _Pragma("unroll") for (int i = 0; i < 4; i++) af[i] = ld128(&Asm[rs][aOff[4 + i]]); \
    if (STG) { gload16(aS1 + kt, (char*)Asm[ss] + aB1);                         \
               gload16(bS1 + kt, (char*)Bsm[ss] + aB1); }                       \
    __builtin_amdgcn_s_barrier();                                               \
    asm volatile("s_waitcnt lgkmcnt(0)" ::: "memory");                          \
    __builtin_amdgcn_sched_barrier(0);                                          \
    __builtin_amdgcn_s_setprio(1);                                              \
    _Pragma("unroll") for (int m = 0; m < 4; m++)                               \
      _Pragma("unroll") for (int n = 0; n < 4; n++)                             \
        acc[4 + m][n] = __builtin_amdgcn_mfma_f32_16x16x32_bf16(af[m], bf[n], acc[4 + m][n], 0, 0, 0); \
    __builtin_amdgcn_s_setprio(0);                                              \
    VMW;                                                                        \
    __builtin_amdgcn_sched_barrier(0);                                          \
    __builtin_amdgcn_s_barrier();                                               \
  }

  {
    int t = 0;
    for (; t < ntk - 3; ++t) KTILE(asm volatile("s_waitcnt vmcnt(8)" ::: "memory"), true);
    KTILE(asm volatile("s_waitcnt vmcnt(4)" ::: "memory"), false); ++t;
    KTILE(asm volatile("s_waitcnt vmcnt(0)" ::: "memory"), false); ++t;
    KTILE((void)0, false);
  }
#undef KTILE

  if (EPI == 2) {
    #pragma unroll
    for (int fm = 0; fm < 8; fm++) {
      #pragma unroll
      for (int fp = 0; fp < 2; fp++) {
        #pragma unroll
        for (int r = 0; r < 4; r++) {
          const size_t row = bx * 256 + wm * 128 + fm * 16 + g * 4 + r;
          const int nb = by * 256 + wn * 64 + fp * 32;
          const int oc = (nb >> 5) * 16 + lrow;
          const float gg = acc[fm][2 * fp][r];
          const float uu = acc[fm][2 * fp + 1][r];
          ((u16*)C)[row * ldc + oc] = f2b(gg / (1.f + __expf(-gg)) * uu);
        }
      }
    }
  } else {
    #pragma unroll
    for (int fm = 0; fm < 8; fm++) {
      #pragma unroll
      for (int fn = 0; fn < 4; fn++) {
        #pragma unroll
        for (int r = 0; r < 4; r++) {
          const size_t row = bx * 256 + wm * 128 + fm * 16 + g * 4 + r;
          const size_t col = by * 256 + wn * 64 + fn * 16 + lrow;
          ((float*)C)[row * ldc + col] = acc[fm][fn][r];
        }
      }
    }
  }
}

// ---------------------------------------------------------------------------
// Small-tile GEMM, 4-slot counted-vmcnt ring.  256 thr = 4 waves.
// EPI: 0 bf16 out; 4 fused QKV-RoPE epilogue (WC must be 64 = one head).
// Requires K/32 >= 4.
// ---------------------------------------------------------------------------
template <int BM, int BN, int WM, int WN, int EPI>
__global__ __launch_bounds__(256) void gemm_k(
    const u16* __restrict__ A, int lda,
    const u16* __restrict__ Bt, int ldb,
    void* __restrict__ C, int ldc,
    const float2* __restrict__ tab, int K)
{
  constexpr int LA = (BM * 4) / 256;      // A gloads per thread per tile
  constexpr int LB = (BN * 4) / 256;      // B gloads per thread per tile
  constexpr int LT = LA + LB;

  __shared__ __align__(16) u16 Asm[4][BM * 32];
  __shared__ __align__(16) u16 Bsm[4][BN * 32];

  const int tid  = threadIdx.x;
  const int lane = tid & 63;
  const int lrow = lane & 15;
  const int kb   = lane >> 4;
  const int w    = tid >> 6;
  const int wm   = w / WN, wn = w % WN;
  constexpr int WR = BM / WM, WC = BN / WN;
  constexpr int FM = WR / 16, FN = WC / 16;

  const u16* aS[LA];
  const u16* bS[LB];
  #pragma unroll
  for (int i = 0; i < LA; i++) {
    const int row = (i * 256 + tid) >> 2, pp = tid & 3;
    const int p = pp ^ ((row ^ (row >> 2)) & 3);
    aS[i] = A + (size_t)(blockIdx.x * BM + row) * lda + p * 8;
  }
  #pragma unroll
  for (int i = 0; i < LB; i++) {
    const int row = (i * 256 + tid) >> 2, pp = tid & 3;
    const int p = pp ^ ((row ^ (row >> 2)) & 3);
    bS[i] = Bt + (size_t)(blockIdx.y * BN + row) * ldb + p * 8;
  }

  int aOff[FM], bOff[FN];
  #pragma unroll
  for (int fm = 0; fm < FM; fm++) {
    const int r = wm * WR + fm * 16 + lrow;
    aOff[fm] = r * 32 + (kb ^ ((r ^ (r >> 2)) & 3)) * 8;
  }
  #pragma unroll
  for (int fn = 0; fn < FN; fn++) {
    const int r = wn * WC + fn * 16 + lrow;
    bOff[fn] = r * 32 + (kb ^ ((r ^ (r >> 2)) & 3)) * 8;
  }

  f32x4 acc[FM][FN] = {};
  const int ntk = K / 32;

  // prologue: stage tiles 0,1,2
  #pragma unroll
  for (int ts = 0; ts < 3; ts++) {
    #pragma unroll
    for (int i = 0; i < LA; i++)
      gload16(aS[i] + ts * 32, (char*)Asm[ts] + (i * 256 + tid) * 16);
    #pragma unroll
    for (int i = 0; i < LB; i++)
      gload16(bS[i] + ts * 32, (char*)Bsm[ts] + (i * 256 + tid) * 16);
  }
  waitvm<2 * LT>();
  __builtin_amdgcn_s_barrier();

#define SKTILE(VMW, STG)                                                        \
  {                                                                             \
    const int rs = t & 3, ss = (t + 3) & 3;                                     \
    const long kt = (long)(t + 3) * 32;                                         \
    bf16x8 af[FM], bf[FN];                                                      \
    _Pragma("unroll") for (int i = 0; i < FN; i++) bf[i] = ld128(&Bsm[rs][bOff[i]]); \
    _Pragma("unroll") for (int i = 0; i < FM; i++) af[i] = ld128(&Asm[rs][aOff[i]]); \
    if (STG) {                                                                  \
      _Pragma("unroll") for (int i = 0; i < LA; i++)                            \
        gload16(aS[i] + kt, (char*)Asm[ss] + (i * 256 + tid) * 16);             \
      _Pragma("unroll") for (int i = 0; i < LB; i++)                            \
        gload16(bS[i] + kt, (char*)Bsm[ss] + (i * 256 + tid) * 16);             \
    }                                                                           \
    __builtin_amdgcn_s_barrier();                                               \
    asm volatile("s_waitcnt lgkmcnt(0)" ::: "memory");                          \
    __builtin_amdgcn_sched_barrier(0);                                          \
    __builtin_amdgcn_s_setprio(1);                                              \
    _Pragma("unroll") for (int m = 0; m < FM; m++)                              \
      _Pragma("unroll") for (int n = 0; n < FN; n++)                            \
        acc[m][n] = __builtin_amdgcn_mfma_f32_16x16x32_bf16(af[m], bf[n], acc[m][n], 0, 0, 0); \
    __builtin_amdgcn_s_setprio(0);                                              \
    VMW;                                                                        \
    __builtin_amdgcn_sched_barrier(0);                                          \
    __builtin_amdgcn_s_barrier();                                               \
  }

  {
    int t = 0;
    for (; t < ntk - 3; ++t) SKTILE(waitvm<2 * LT>(), true);
    SKTILE(waitvm<LT>(), false); ++t;
    SKTILE(waitvm<0>(), false); ++t;
    SKTILE((void)0, false);
  }
#undef SKTILE

  if (EPI == 4) {
    const int colb = blockIdx.y * BN + wn * WC;
    const int head = colb >> 6;                          // 0..31
    const float qs = (head < 16) ? 0.125f : 1.0f;
    #pragma unroll
    for (int fm = 0; fm < FM; fm++) {
      #pragma unroll
      for (int r = 0; r < 4; r++) {
        const int row = blockIdx.x * BM + wm * WR + fm * 16 + kb * 4 + r;
        if (head >= 24) {   // v heads: no rope
          #pragma unroll
          for (int fn = 0; fn < FN; fn++)
            ((u16*)C)[row * ldc + colb + fn * 16 + lrow] = f2b(acc[fm][fn][r]);
        } else {
          const int s = row & (S - 1);
          #pragma unroll
          for (int fp = 0; fp < 2; fp++) {
            const int d = fp * 16 + lrow;               // 0..31
            const float2 cs = tab[s * 32 + d];
            const float x1 = acc[fm][fp][r];
            const float x2 = acc[fm][fp + 2][r];
            ((u16*)C)[row * ldc + colb + d]      = f2b((x1 * cs.x - x2 * cs.y) * qs);
            ((u16*)C)[row * ldc + colb + d + 32] = f2b((x2 * cs.x + x1 * cs.y) * qs);
          }
        }
      }
    }
  } else {
    #pragma unroll
    for (int fm = 0; fm < FM; fm++) {
      #pragma unroll
      for (int fn = 0; fn < FN; fn++) {
        #pragma unroll
        for (int r = 0; r < 4; r++) {
          const int row = blockIdx.x * BM + wm * WR + fm * 16 + kb * 4 + r;
          const int col = blockIdx.y * BN + wn * WC + fn * 16 + lrow;
          ((u16*)C)[row * ldc + col] = f2b(acc[fm][fn][r]);
        }
      }
    }
  }
}

// ---------------------------------------------------------------------------
// Layer-batched transpose-convert: W[z][K][N] f32 -> WT[z][rowmap(n)][K] bf16
// rmode: 0 identity; 1 gate-interleave; 2 up-interleave.
// ---------------------------------------------------------------------------
__global__ __launch_bounds__(256) void transpose_k(
    const float* __restrict__ W, u16* __restrict__ WT, int K, int N, int rmode,
    size_t wstride, size_t tstride)
{
  __shared__ float t[32][33];
  const float* Wp = W + (size_t)blockIdx.z * wstride;
  u16* WTp = WT + (size_t)blockIdx.z * tstride;
  const int k0 = blockIdx.x * 32, n0 = blockIdx.y * 32;
  const int tx = threadIdx.x & 31, ty = threadIdx.x >> 5;
  #pragma unroll
  for (int i = 0; i < 32; i += 8)
    t[ty + i][tx] = Wp[(size_t)(k0 + ty + i) * N + (n0 + tx)];
  __syncthreads();
  #pragma unroll
  for (int i = 0; i < 32; i += 8) {
    const int n = n0 + ty + i;
    const int orow = (rmode == 0) ? n : ((n >> 4) * 32 + (n & 15) + ((rmode == 2) ? 16 : 0));
    WTp[(size_t)orow * K + (k0 + tx)] = f2b(t[tx][ty + i]);
  }
}

// ---------------------------------------------------------------------------
__global__ __launch_bounds__(256) void embed_k(
    const int* __restrict__ ids, const float* __restrict__ E, float* __restrict__ h)
{
  const int t = blockIdx.x;
  const int id = ids[t];
  ((float4*)(h + t * H))[threadIdx.x] = ((const float4*)(E + (size_t)id * H))[threadIdx.x];
}

// ---------------------------------------------------------------------------
__global__ __launch_bounds__(256) void rmsnorm_k(
    const float* __restrict__ h, const float* __restrict__ w, u16* __restrict__ x)
{
  const int row = blockIdx.x;
  const float4 hv = ((const float4*)(h + row * H))[threadIdx.x];
  float s = hv.x * hv.x + hv.y * hv.y + hv.z * hv.z + hv.w * hv.w;
  #pragma unroll
  for (int off = 32; off; off >>= 1) s += __shfl_xor(s, off, 64);
  __shared__ float red[4];
  if ((threadIdx.x & 63) == 0) red[threadIdx.x >> 6] = s;
  __syncthreads();
  s = red[0] + red[1] + red[2] + red[3];
  const float scale = rsqrtf(s * (1.f / H) + 1e-6f);
  const float4 wv = ((const float4*)w)[threadIdx.x];
  ushort4 ov;
  ov.x = f2b(hv.x * scale * wv.x);
  ov.y = f2b(hv.y * scale * wv.y);
  ov.z = f2b(hv.z * scale * wv.z);
  ov.w = f2b(hv.w * scale * wv.w);
  ((ushort4*)(x + row * H))[threadIdx.x] = ov;
}

// ---------------------------------------------------------------------------
// Fused residual add + RMSNorm: h += dl (bf16 delta); x = rms(h)*w.
// ---------------------------------------------------------------------------
__global__ __launch_bounds__(256) void addnorm_k(
    float* __restrict__ h, const u16* __restrict__ dl,
    const float* __restrict__ w, u16* __restrict__ x)
{
  const int row = blockIdx.x;
  float4 hv = ((const float4*)(h + row * H))[threadIdx.x];
  const ushort4 dv = ((const ushort4*)(dl + row * H))[threadIdx.x];
  hv.x += b2f(dv.x); hv.y += b2f(dv.y); hv.z += b2f(dv.z); hv.w += b2f(dv.w);
  ((float4*)(h + row * H))[threadIdx.x] = hv;
  float s = hv.x * hv.x + hv.y * hv.y + hv.z * hv.z + hv.w * hv.w;
  #pragma unroll
  for (int off = 32; off; off >>= 1) s += __shfl_xor(s, off, 64);
  __shared__ float red[4];
  if ((threadIdx.x & 63) == 0) red[threadIdx.x >> 6] = s;
  __syncthreads();
  s = red[0] + red[1] + red[2] + red[3];
  const float scale = rsqrtf(s * (1.f / H) + 1e-6f);
  const float4 wv = ((const float4*)w)[threadIdx.x];
  ushort4 ov;
  ov.x = f2b(hv.x * scale * wv.x);
  ov.y = f2b(hv.y * scale * wv.y);
  ov.z = f2b(hv.z * scale * wv.z);
  ov.w = f2b(hv.w * scale * wv.w);
  ((ushort4*)(x + row * H))[threadIdx.x] = ov;
}

// ---------------------------------------------------------------------------
__global__ __launch_bounds__(256) void ropetab_k(float2* __restrict__ tab)
{
  const int idx = blockIdx.x * 256 + threadIdx.x;
  const int s = idx >> 5, d = idx & 31;
  const float ang = s * powf(10000.f, -(2.f * d) / 64.f);
  float sn, cs;
  sincosf(ang, &sn, &cs);
  tab[idx] = make_float2(cs, sn);
}

// ---------------------------------------------------------------------------
// Flash attention v2.  512 blocks (one per (q-tile, bh)), 256 thr = 4 waves.
// XCD-aware bh grouping; long q-tiles first; defer-max rescale skip.
// ---------------------------------------------------------------------------
__global__ __launch_bounds__(256) void fattn_k(
    const u16* __restrict__ qkv, u16* __restrict__ o)
{
  __shared__ __align__(16) u16 Ks[64 * 64];
  __shared__ __align__(16) u16 Vt[64 * 72];
  __shared__ __align__(16) u16 Pw[4][16 * 64];

  const int tid  = threadIdx.x;
  const int lane = tid & 63;
  const int lrow = lane & 15;
  const int g    = lane >> 4;
  const int w    = tid >> 6;

  const int bid = blockIdx.x;                 // 0..511
  const int j   = bid >> 3;
  const int bh  = (bid & 7) * 4 + (j & 3);    // 0..31
  const int bx  = 15 - (j >> 2);              // long q-tiles first
  const int b = bh >> 4, hh = bh & 15, kh = hh >> 1;
  const int q0 = bx * 64;

  bf16x8 aq[2];
  {
    const int qrow = q0 + w * 16 + lrow;
    const u16* qp = qkv + (size_t)(b * S + qrow) * QKVW + hh * 64 + g * 8;
    aq[0] = *reinterpret_cast<const bf16x8*>(qp);
    aq[1] = *reinterpret_cast<const bf16x8*>(qp + 32);
  }

  f32x4 oacc[4] = {};
  float mrow[4], lsum[4];
  #pragma unroll
  for (int r = 0; r < 4; r++) { mrow[r] = -1e30f; lsum[r] = 0.f; }

  const int nt = bx + 1;
  for (int t = 0; t < nt; t++) {
    const int kv0 = t * 64;
    __syncthreads();   // prev-iter LDS reads complete

    #pragma unroll
    for (int i = 0; i < 2; i++) {
      const int c = i * 256 + tid;
      const int r = c >> 3, p = c & 7;
      gload16(qkv + (size_t)(b * S + kv0 + r) * QKVW + 1024 + kh * 64 + ((p ^ (r & 7)) * 8),
              (char*)Ks + c * 16);
    }
    u16x8 vreg[2];
    #pragma unroll
    for (int i = 0; i < 2; i++) {
      const int c = i * 256 + tid;
      const int k = c >> 3, dch = c & 7;
      vreg[i] = *reinterpret_cast<const u16x8*>(
          qkv + (size_t)(b * S + kv0 + k) * QKVW + 1536 + kh * 64 + dch * 8);
    }
    #pragma unroll
    for (int i = 0; i < 2; i++) {
      const int c = i * 256 + tid;
      const int k = c >> 3, d0 = (c & 7) * 8;
      #pragma unroll
      for (int j2 = 0; j2 < 8; j2++) {
        const int d = d0 + j2;
        Vt[d * 72 + (((k >> 3) ^ (d >> 3)) * 8) + (k & 7)] = vreg[i][j2];
      }
    }
    __syncthreads();

    f32x4 sacc[4] = {};
    #pragma unroll
    for (int n = 0; n < 4; n++) {
      const int row = n * 16 + lrow;
      #pragma unroll
      for (int k2 = 0; k2 < 2; k2++) {
        const bf16x8 bk = *reinterpret_cast<const bf16x8*>(
            Ks + row * 64 + (((k2 * 4 + g) ^ (row & 7)) * 8));
        sacc[n] = __builtin_amdgcn_mfma_f32_16x16x32_bf16(aq[k2], bk, sacc[n], 0, 0, 0);
      }
    }

    float rmv[4];
    #pragma unroll
    for (int r = 0; r < 4; r++) {
      const int qglob = q0 + w * 16 + g * 4 + r;
      float rm = -1e30f;
      #pragma unroll
      for (int n = 0; n < 4; n++) {
        const int kg = kv0 + n * 16 + lrow;
        if (kg > qglob) sacc[n][r] = -1e30f;
        rm = fmaxf(rm, sacc[n][r]);
      }
      #pragma unroll
      for (int mk = 1; mk < 16; mk <<= 1) rm = fmaxf(rm, __shfl_xor(rm, mk, 64));
      rmv[r] = rm;
    }

    int need = 0;
    #pragma unroll
    for (int r = 0; r < 4; r++) need |= (rmv[r] > mrow[r] + 8.f) ? 1 : 0;
    if (__any(need)) {
      #pragma unroll
      for (int r = 0; r < 4; r++) {
        const float mnew  = fmaxf(mrow[r], rmv[r]);
        const float scale = __expf(mrow[r] - mnew);
        mrow[r] = mnew;
        lsum[r] *= scale;
        #pragma unroll
        for (int dt = 0; dt < 4; dt++) oacc[dt][r] *= scale;
      }
    }

    #pragma unroll
    for (int r = 0; r < 4; r++) {
      float rs = 0.f;
      u16 pb[4];
      #pragma unroll
      for (int n = 0; n < 4; n++) {
        const float p = __expf(sacc[n][r] - mrow[r]);
        rs += p;
        pb[n] = f2b(p);
      }
      #pragma unroll
      for (int mk = 1; mk < 16; mk <<= 1) rs += __shfl_xor(rs, mk, 64);
      lsum[r] += rs;
      const int ql = g * 4 + r;
      #pragma unroll
      for (int n = 0; n < 4; n++) {
        const int k = n * 16 + lrow;
        Pw[w][ql * 64 + (((k >> 3) ^ (ql & 7)) * 8) + (k & 7)] = pb[n];
      }
    }

    #pragma unroll
    for (int k2 = 0; k2 < 2; k2++) {
      const bf16x8 pa = *reinterpret_cast<const bf16x8*>(
          &Pw[w][lrow * 64 + (((k2 * 4 + g) ^ (lrow & 7)) * 8)]);
      #pragma unroll
      for (int dt = 0; dt < 4; dt++) {
        const int d = dt * 16 + lrow;
        const bf16x8 vb = *reinterpret_cast<const bf16x8*>(
            &Vt[d * 72 + (((k2 * 4 + g) ^ (d >> 3)) * 8)]);
        oacc[dt] = __builtin_amdgcn_mfma_f32_16x16x32_bf16(pa, vb, oacc[dt], 0, 0, 0);
      }
    }
  }

  #pragma unroll
  for (int dt = 0; dt < 4; dt++) {
    #pragma unroll
    for (int r = 0; r < 4; r++) {
      const int qrow = q0 + w * 16 + g * 4 + r;
      o[(size_t)(b * S + qrow) * H + hh * 64 + dt * 16 + lrow] =
          f2b(oacc[dt][r] / lsum[r]);
    }
  }
}

// ---------------------------------------------------------------------------
extern "C" void kernel_launch(void* const* d_in, const int* in_sizes, int n_in,
                              void* d_out, int out_size, void* d_ws, size_t ws_size,
                              hipStream_t stream)
{
  const int*   ids  = (const int*)d_in[0];
  const float* EW   = (const float*)d_in[1];
  const float* Wq   = (const float*)d_in[2];
  const float* Wk   = (const float*)d_in[3];
  const float* Wv   = (const float*)d_in[4];
  const float* Wo   = (const float*)d_in[5];
  const float* Wg   = (const float*)d_in[6];
  const float* Wu   = (const float*)d_in[7];
  const float* Wd   = (const float*)d_in[8];
  const float* ln1  = (const float*)d_in[9];
  const float* ln2  = (const float*)d_in[10];
  const float* nw   = (const float*)d_in[11];
  const float* lmw  = (const float*)d_in[12];
  float* out = (float*)d_out;

  const size_t MB = 1u << 20;
  char* ws = (char*)d_ws;
  float*  h   = (float*)(ws);                  // 8 MiB  [NT][H] f32
  u16*    x   = (u16*)(ws + 8 * MB);           // 4 MiB  [NT][H]
  u16*    qkv = (u16*)(ws + 12 * MB);          // 8 MiB  [NT][2048]
  u16*    o   = (u16*)(ws + 20 * MB);          // 4 MiB  [NT][H]
  u16*    dl  = (u16*)(ws + 24 * MB);          // 4 MiB  [NT][H]
  u16*    ub  = (u16*)(ws + 28 * MB);          // 16 MiB [NT][4096]
  float2* tab = (float2*)(ws + 44 * MB);       // 256 KiB
  char*   wb  = ws + 45 * MB;

  const size_t sqkv = (size_t)QKVW * H;        // elems per layer (4 MiB)
  const size_t swo  = (size_t)H * H;           // 2 MiB
  const size_t sgu  = (size_t)2 * FF * H;      // 16 MiB
  const size_t swd  = (size_t)H * FF;          // 8 MiB

  const bool full = ws_size >= 349 * MB;
  if (!full && ws_size < 108 * MB) return;     // cannot run; fail loudly

  u16 *wqkvT, *woT, *wguT, *wdT, *lmT;
  if (full) {
    wqkvT = (u16*)wb;                          // 32 MiB
    woT   = wqkvT + NL * sqkv;                 // 16 MiB
    wguT  = woT + NL * swo;                    // 128 MiB
    wdT   = wguT + NL * sgu;                   // 64 MiB
    lmT   = wdT + NL * swd;                    // 62.5 MiB
  } else {
    wqkvT = (u16*)wb;
    woT   = wqkvT + sqkv;
    wguT  = woT + swo;
    wdT   = wguT + sgu;
    lmT   = (u16*)wb;                          // reused after the layer loop
  }

  auto xpose = [&](int l0, int lz, bool dense) {
    const size_t tq = dense ? sqkv : 0, to = dense ? swo : 0;
    const size_t tg = dense ? sgu : 0,  td = dense ? swd : 0;
    transpose_k<<<dim3(H / 32, H / 32, lz), 256, 0, stream>>>(
        Wq + (size_t)l0 * H * H, wqkvT + (size_t)l0 * tq, H, H, 0, (size_t)H * H, tq);
    transpose_k<<<dim3(H / 32, 512 / 32, lz), 256, 0, stream>>>(
        Wk + (size_t)l0 * H * 512, wqkvT + (size_t)l0 * tq + (size_t)1024 * H, H, 512, 0,
        (size_t)H * 512, tq);
    transpose_k<<<dim3(H / 32, 512 / 32, lz), 256, 0, stream>>>(
        Wv + (size_t)l0 * H * 512, wqkvT + (size_t)l0 * tq + (size_t)1536 * H, H, 512, 0,
        (size_t)H * 512, tq);
    transpose_k<<<dim3(H / 32, H / 32, lz), 256, 0, stream>>>(
        Wo + (size_t)l0 * H * H, woT + (size_t)l0 * to, H, H, 0, (size_t)H * H, to);
    transpose_k<<<dim3(H / 32, FF / 32, lz), 256, 0, stream>>>(
        Wg + (size_t)l0 * H * FF, wguT + (size_t)l0 * tg, H, FF, 1, (size_t)H * FF, tg);
    transpose_k<<<dim3(H / 32, FF / 32, lz), 256, 0, stream>>>(
        Wu + (size_t)l0 * H * FF, wguT + (size_t)l0 * tg, H, FF, 2, (size_t)H * FF, tg);
    transpose_k<<<dim3(FF / 32, H / 32, lz), 256, 0, stream>>>(
        Wd + (size_t)l0 * FF * H, wdT + (size_t)l0 * td, FF, H, 0, (size_t)FF * H, td);
  };

  embed_k<<<NT, 256, 0, stream>>>(ids, EW, h);
  ropetab_k<<<(S * 32) / 256, 256, 0, stream>>>(tab);

  if (full) {
    xpose(0, NL, true);
    transpose_k<<<dim3(H / 32, V / 32, 1), 256, 0, stream>>>(lmw, lmT, H, V, 0, 0, 0);
  }

  // x for layer 0
  rmsnorm_k<<<NT, 256, 0, stream>>>(h, ln1, x);

  for (int l = 0; l < NL; l++) {
    if (!full) xpose(l, 1, false);
    u16* pq = wqkvT + (full ? (size_t)l * sqkv : 0);
    u16* po = woT   + (full ? (size_t)l * swo  : 0);
    u16* pg = wguT  + (full ? (size_t)l * sgu  : 0);
    u16* pd = wdT   + (full ? (size_t)l * swd  : 0);

    // ---- attention ----
    gemm_k<64, 128, 2, 2, 4><<<dim3(NT / 64, QKVW / 128), 256, 0, stream>>>(
        x, H, pq, H, qkv, QKVW, tab, H);
    fattn_k<<<dim3(512), 256, 0, stream>>>(qkv, o);
    gemm_k<64, 64, 2, 2, 0><<<dim3(NT / 64, H / 64), 256, 0, stream>>>(
        o, H, po, H, dl, H, nullptr, H);
    addnorm_k<<<NT, 256, 0, stream>>>(h, dl, ln2 + l * H, x);

    // ---- MLP ----
    gemm256_k<2><<<dim3(NT / 256, (2 * FF) / 256), 512, 0, stream>>>(
        x, H, pg, H, ub, FF, H);
    gemm_k<64, 64, 2, 2, 0><<<dim3(NT / 64, H / 64), 256, 0, stream>>>(
        ub, FF, pd, FF, dl, H, nullptr, FF);
    const float* nxt = (l + 1 < NL) ? (ln1 + (l + 1) * H) : nw;
    addnorm_k<<<NT, 256, 0, stream>>>(h, dl, nxt, x);
  }

  if (!full)
    transpose_k<<<dim3(H / 32, V / 32, 1), 256, 0, stream>>>(lmw, lmT, H, V, 0, 0, 0);
  gemm256_k<3><<<dim3(NT / 256, V / 256), 512, 0, stream>>>(
      x, H, lmT, H, out, V, H);
}